// Round 1
// baseline (428.980 us; speedup 1.0000x reference)
//
#include <hip/hip_runtime.h>
#include <math.h>

#define NPTS 16384
#define KNN  16
#define SEQV 8

__device__ __forceinline__ unsigned umin_(unsigned a, unsigned b) { return a < b ? a : b; }
__device__ __forceinline__ unsigned umax_(unsigned a, unsigned b) { return a > b ? a : b; }

// ---------------------------------------------------------------------------
// Kernel 1: partial kNN. Grid (NPTS/256, nparts). Thread = one query point,
// scans candidate range [p*plen, (p+1)*plen) keeping a sorted top-16 of packed
// keys:  key = (float_bits(d2) & 0xFFFFC000) | j   (j < 2^14).
// Candidate coords are wave-uniform -> scalar loads (readfirstlane).
// ---------------------------------------------------------------------------
__global__ __launch_bounds__(256) void knn_partial_kernel(
    const float* __restrict__ pc, unsigned* __restrict__ part, int plen)
{
    const int i = blockIdx.x * 256 + threadIdx.x;   // query index
    const int p = blockIdx.y;                       // candidate partition

    const float qx = pc[3 * i + 0];
    const float qy = pc[3 * i + 1];
    const float qz = pc[3 * i + 2];

    unsigned keys[KNN];
#pragma unroll
    for (int t = 0; t < KNN; ++t) keys[t] = 0xFFFFFFFFu;

    const int jbeg = p * plen;
    const int jend = jbeg + plen;

    for (int j = jbeg; j < jend; j += 4) {
        unsigned kb[4];
#pragma unroll
        for (int q = 0; q < 4; ++q) {
            int ju = __builtin_amdgcn_readfirstlane(j + q);
            float cx = pc[3 * ju + 0];
            float cy = pc[3 * ju + 1];
            float cz = pc[3 * ju + 2];
            float dx = qx - cx, dy = qy - cy, dz = qz - cz;
            float d2 = fmaf(dx, dx, fmaf(dy, dy, dz * dz));
            kb[q] = (__float_as_uint(d2) & 0xFFFFC000u) | (unsigned)(j + q);
        }
#pragma unroll
        for (int q = 0; q < 4; ++q) {
            unsigned key = kb[q];
            if (key < keys[KNN - 1]) {
#pragma unroll
                for (int u = 0; u < KNN; ++u) {
                    unsigned lo = umin_(key, keys[u]);
                    key = umax_(key, keys[u]);
                    keys[u] = lo;
                }
            }
        }
    }

    unsigned* dst = part + ((size_t)p * NPTS + i) * KNN;
#pragma unroll
    for (int t = 0; t < KNN; ++t) dst[t] = keys[t];
}

// ---------------------------------------------------------------------------
// Kernel 2: merge partitions -> final top-16, radius replace, fused loss.
// accum[0] += sum_{s,k} w_i * norm(s,i,k);  accum[1] += w_i
// ---------------------------------------------------------------------------
__global__ __launch_bounds__(256) void merge_loss_kernel(
    const float* __restrict__ flow,      // (SEQ, N, 3)
    const float* __restrict__ w,         // (N,)
    const unsigned* __restrict__ part,   // (nparts, N, KNN)
    int nparts,
    float* __restrict__ accum)
{
    const int i = blockIdx.x * 256 + threadIdx.x;

    unsigned keys[KNN];
#pragma unroll
    for (int t = 0; t < KNN; ++t) keys[t] = part[(size_t)i * KNN + t];

    for (int p = 1; p < nparts; ++p) {
        const unsigned* src = part + ((size_t)p * NPTS + i) * KNN;
#pragma unroll
        for (int t = 0; t < KNN; ++t) {
            unsigned key = src[t];
            if (key < keys[KNN - 1]) {
#pragma unroll
                for (int u = 0; u < KNN; ++u) {
                    unsigned lo = umin_(key, keys[u]);
                    key = umax_(key, keys[u]);
                    keys[u] = lo;
                }
            }
        }
    }

    // radius filter: if sqrt(d2) > 1.0  (<=> d2 > 1.0) use nearest neighbor idx
    int ids[KNN];
    const int id0 = (int)(keys[0] & 0x3FFFu);
#pragma unroll
    for (int t = 0; t < KNN; ++t) {
        float d2t = __uint_as_float(keys[t] & 0xFFFFC000u);
        int   j   = (int)(keys[t] & 0x3FFFu);
        ids[t] = (d2t > 1.0f) ? id0 : j;
    }

    float sum = 0.0f;
    for (int s = 0; s < SEQV; ++s) {
        const float* fs = flow + (size_t)s * NPTS * 3;
        float fx = fs[3 * i + 0];
        float fy = fs[3 * i + 1];
        float fz = fs[3 * i + 2];
#pragma unroll
        for (int t = 0; t < KNN; ++t) {
            int j = ids[t];
            float dx = fx - fs[3 * j + 0];
            float dy = fy - fs[3 * j + 1];
            float dz = fz - fs[3 * j + 2];
            float sq = fmaf(dx, dx, fmaf(dy, dy, dz * dz));
            sum += (sq > 0.0f) ? sqrtf(sq) : 0.0f;
        }
    }

    float wi = w[i];
    float contrib = wi * sum;

    // wave (64) reduction, then cross-wave via LDS
#pragma unroll
    for (int off = 32; off > 0; off >>= 1) {
        contrib += __shfl_down(contrib, off);
        wi      += __shfl_down(wi, off);
    }
    __shared__ float sc[4], sw[4];
    const int lane = threadIdx.x & 63;
    const int wv   = threadIdx.x >> 6;
    if (lane == 0) { sc[wv] = contrib; sw[wv] = wi; }
    __syncthreads();
    if (threadIdx.x == 0) {
        float c  = sc[0] + sc[1] + sc[2] + sc[3];
        float ww = sw[0] + sw[1] + sw[2] + sw[3];
        atomicAdd(&accum[0], c);
        atomicAdd(&accum[1], ww);
    }
}

// ---------------------------------------------------------------------------
// Kernel 3: finalize.  out = accum0 / (K*SEQ*wsum)   (guard wsum<=0 like ref)
// ---------------------------------------------------------------------------
__global__ void finalize_kernel(const float* __restrict__ accum, float* __restrict__ out)
{
    float a  = accum[0];
    float ws = accum[1];
    float v  = a / (float)(KNN * SEQV);
    out[0] = (ws > 0.0f) ? (v / ws) : v;
}

extern "C" void kernel_launch(void* const* d_in, const int* in_sizes, int n_in,
                              void* d_out, int out_size, void* d_ws, size_t ws_size,
                              hipStream_t stream)
{
    const float* pc   = (const float*)d_in[0];   // (1, N, 3)
    const float* flow = (const float*)d_in[1];   // (SEQ, N, 3)
    const float* wts  = (const float*)d_in[2];   // (N,)
    float* out = (float*)d_out;

    float*    accum = (float*)d_ws;
    unsigned* part  = (unsigned*)((char*)d_ws + 256);

    // pick partition count that fits in workspace (prefer 8)
    int nparts = 8;
    while (nparts > 1 &&
           (size_t)nparts * NPTS * KNN * sizeof(unsigned) + 256 > ws_size) {
        nparts >>= 1;
    }
    const int plen = NPTS / nparts;

    hipMemsetAsync(d_ws, 0, 64, stream);

    dim3 g1(NPTS / 256, nparts);
    knn_partial_kernel<<<g1, 256, 0, stream>>>(pc, part, plen);
    merge_loss_kernel<<<NPTS / 256, 256, 0, stream>>>(flow, wts, part, nparts, accum);
    finalize_kernel<<<1, 1, 0, stream>>>(accum, out);
}

// Round 2
// 374.732 us; speedup vs baseline: 1.1448x; 1.1448x over previous
//
#include <hip/hip_runtime.h>
#include <math.h>

#define NPTS 16384
#define KNN  16
#define SEQV 8
#define CAP  40      // per-thread LDS candidate buffer (40*4*256 = 40 KB/block)

__device__ __forceinline__ unsigned umin_(unsigned a, unsigned b) { return a < b ? a : b; }
__device__ __forceinline__ unsigned umax_(unsigned a, unsigned b) { return a > b ? a : b; }

// merge one key into sorted ascending keys[16] (branch + full min/max chain)
__device__ __forceinline__ void merge_one(unsigned keys[KNN], unsigned kk) {
    if (kk < keys[KNN - 1]) {
#pragma unroll
        for (int u = 0; u < KNN; ++u) {
            unsigned lo = umin_(kk, keys[u]);
            kk = umax_(kk, keys[u]);
            keys[u] = lo;
        }
    }
}

// ---------------------------------------------------------------------------
// A: cold sample scan. Grid (64, nparts). Partition p scans its first `samp`
// candidates, writes top-16 packed keys. key = (d2 bits & 0xFFFFC000) | j.
// ---------------------------------------------------------------------------
__global__ __launch_bounds__(256) void knn_sample_kernel(
    const float* __restrict__ pc, unsigned* __restrict__ part, int plen, int samp)
{
    const int i = blockIdx.x * 256 + threadIdx.x;
    const int p = blockIdx.y;

    const float qx = pc[3 * i + 0];
    const float qy = pc[3 * i + 1];
    const float qz = pc[3 * i + 2];

    unsigned keys[KNN];
#pragma unroll
    for (int t = 0; t < KNN; ++t) keys[t] = 0xFFFFFFFFu;

    const int jbeg = p * plen;
    const int jend = jbeg + samp;

    for (int j = jbeg; j < jend; j += 4) {
        unsigned kb[4];
#pragma unroll
        for (int q = 0; q < 4; ++q) {
            int ju = __builtin_amdgcn_readfirstlane(j + q);
            float cx = pc[3 * ju + 0];
            float cy = pc[3 * ju + 1];
            float cz = pc[3 * ju + 2];
            float dx = qx - cx, dy = qy - cy, dz = qz - cz;
            float d2 = fmaf(dx, dx, fmaf(dy, dy, dz * dz));
            kb[q] = (__float_as_uint(d2) & 0xFFFFC000u) | (unsigned)(j + q);
        }
#pragma unroll
        for (int q = 0; q < 4; ++q) merge_one(keys, kb[q]);
    }

    unsigned* dst = part + ((size_t)p * NPTS + i) * KNN;
#pragma unroll
    for (int t = 0; t < KNN; ++t) dst[t] = keys[t];
}

// ---------------------------------------------------------------------------
// A2: tau[i] = 16th-smallest key of the sample (merge nparts x 16 partials).
// Also accumulates the weight sum (once).
// ---------------------------------------------------------------------------
__global__ __launch_bounds__(256) void tau_kernel(
    const unsigned* __restrict__ part, const float* __restrict__ w, int nparts,
    float* __restrict__ accum, unsigned* __restrict__ tauArr)
{
    const int i = blockIdx.x * 256 + threadIdx.x;

    unsigned keys[KNN];
#pragma unroll
    for (int t = 0; t < KNN; ++t) keys[t] = 0xFFFFFFFFu;

#pragma unroll 1
    for (int p = 0; p < nparts; ++p) {
        const unsigned* src = part + ((size_t)p * NPTS + i) * KNN;
#pragma unroll
        for (int t = 0; t < KNN; ++t) merge_one(keys, src[t]);
    }
    tauArr[i] = keys[KNN - 1];

    float wi = w[i];
#pragma unroll
    for (int off = 32; off > 0; off >>= 1) wi += __shfl_down(wi, off);
    if ((threadIdx.x & 63) == 0) atomicAdd(&accum[1], wi);
}

// ---------------------------------------------------------------------------
// B: main scan with threshold filter + deferred LDS-buffered selection.
// Grid (64, nparts). Software-pipelined candidate loads (U=8).
// ---------------------------------------------------------------------------
__global__ __launch_bounds__(256) void knn_main_kernel(
    const float* __restrict__ pc, const unsigned* __restrict__ tauArr,
    unsigned* __restrict__ part, int plen)
{
    __shared__ unsigned sbuf[256 * CAP];
    unsigned* buf = &sbuf[threadIdx.x * CAP];

    const int i = blockIdx.x * 256 + threadIdx.x;
    const int p = blockIdx.y;

    const float qx = pc[3 * i + 0];
    const float qy = pc[3 * i + 1];
    const float qz = pc[3 * i + 2];

    unsigned tau = tauArr[i];
    unsigned keys[KNN];
#pragma unroll
    for (int t = 0; t < KNN; ++t) keys[t] = 0xFFFFFFFFu;
    int cnt = 0;

    const int jbeg = p * plen;
    const int jend = jbeg + plen;
    const int U = 8;

    float cx[U], cy[U], cz[U];
#pragma unroll
    for (int q = 0; q < U; ++q) {
        int ju = __builtin_amdgcn_readfirstlane(jbeg + q);
        cx[q] = pc[3 * ju + 0];
        cy[q] = pc[3 * ju + 1];
        cz[q] = pc[3 * ju + 2];
    }

#pragma unroll 1
    for (int j = jbeg; j < jend; j += U) {
        float nx[U], ny[U], nz[U];
        const int jn = j + U;
        if (jn < jend) {
#pragma unroll
            for (int q = 0; q < U; ++q) {
                int ju = __builtin_amdgcn_readfirstlane(jn + q);
                nx[q] = pc[3 * ju + 0];
                ny[q] = pc[3 * ju + 1];
                nz[q] = pc[3 * ju + 2];
            }
        }
#pragma unroll
        for (int q = 0; q < U; ++q) {
            float dx = qx - cx[q], dy = qy - cy[q], dz = qz - cz[q];
            float d2 = fmaf(dx, dx, fmaf(dy, dy, dz * dz));
            unsigned key = (__float_as_uint(d2) & 0xFFFFC000u) | (unsigned)(j + q);
            if (key <= tau) {          // tau >= global 16th key -> exact
                buf[cnt] = key;
                cnt++;
            }
        }
        // guaranteed-headroom compaction: entering a batch cnt <= CAP-U-1
        if (cnt >= CAP - U) {
#pragma unroll 1
            for (int t = 0; t < cnt; ++t) merge_one(keys, buf[t]);
            cnt = 0;
            tau = umin_(tau, keys[KNN - 1]);   // still >= global 16th key
        }
#pragma unroll
        for (int q = 0; q < U; ++q) { cx[q] = nx[q]; cy[q] = ny[q]; cz[q] = nz[q]; }
    }

#pragma unroll 1
    for (int t = 0; t < cnt; ++t) merge_one(keys, buf[t]);

    unsigned* dst = part + ((size_t)p * NPTS + i) * KNN;
#pragma unroll
    for (int t = 0; t < KNN; ++t) dst[t] = keys[t];
}

// ---------------------------------------------------------------------------
// D: fused merge + radius + loss. Grid (64, SEQV); block handles one s.
// accum[0] += sum_i w_i * sum_k norm(s,i,k)
// ---------------------------------------------------------------------------
__global__ __launch_bounds__(256) void loss_kernel(
    const float* __restrict__ flow, const float* __restrict__ w,
    const unsigned* __restrict__ part, int nparts, float* __restrict__ accum)
{
    const int i = blockIdx.x * 256 + threadIdx.x;
    const int s = blockIdx.y;

    unsigned keys[KNN];
#pragma unroll
    for (int t = 0; t < KNN; ++t) keys[t] = 0xFFFFFFFFu;

#pragma unroll 1
    for (int p = 0; p < nparts; ++p) {
        const unsigned* src = part + ((size_t)p * NPTS + i) * KNN;
#pragma unroll
        for (int t = 0; t < KNN; ++t) merge_one(keys, src[t]);
    }

    // radius filter (d2 > 1)  -> replace with nearest idx
    int ids[KNN];
    const int id0 = (int)(keys[0] & 0x3FFFu);
#pragma unroll
    for (int t = 0; t < KNN; ++t) {
        float d2t = __uint_as_float(keys[t] & 0xFFFFC000u);
        int   j   = (int)(keys[t] & 0x3FFFu);
        ids[t] = (d2t > 1.0f) ? id0 : j;
    }

    const float* fs = flow + (size_t)s * NPTS * 3;
    const float fx = fs[3 * i + 0];
    const float fy = fs[3 * i + 1];
    const float fz = fs[3 * i + 2];

    float sum = 0.0f;
#pragma unroll
    for (int t = 0; t < KNN; ++t) {
        int j = ids[t];
        float dx = fx - fs[3 * j + 0];
        float dy = fy - fs[3 * j + 1];
        float dz = fz - fs[3 * j + 2];
        float sq = fmaf(dx, dx, fmaf(dy, dy, dz * dz));
        sum += (sq > 0.0f) ? sqrtf(sq) : 0.0f;
    }

    float contrib = w[i] * sum;
#pragma unroll
    for (int off = 32; off > 0; off >>= 1) contrib += __shfl_down(contrib, off);

    __shared__ float sc[4];
    const int lane = threadIdx.x & 63;
    const int wv   = threadIdx.x >> 6;
    if (lane == 0) sc[wv] = contrib;
    __syncthreads();
    if (threadIdx.x == 0)
        atomicAdd(&accum[0], sc[0] + sc[1] + sc[2] + sc[3]);
}

__global__ void finalize_kernel(const float* __restrict__ accum, float* __restrict__ out)
{
    float a  = accum[0];
    float ws = accum[1];
    float v  = a / (float)(KNN * SEQV);
    out[0] = (ws > 0.0f) ? (v / ws) : v;
}

extern "C" void kernel_launch(void* const* d_in, const int* in_sizes, int n_in,
                              void* d_out, int out_size, void* d_ws, size_t ws_size,
                              hipStream_t stream)
{
    const float* pc   = (const float*)d_in[0];   // (1, N, 3)
    const float* flow = (const float*)d_in[1];   // (SEQ, N, 3)
    const float* wts  = (const float*)d_in[2];   // (N,)
    float* out = (float*)d_out;

    float*    accum  = (float*)d_ws;
    unsigned* tauArr = (unsigned*)((char*)d_ws + 256);
    unsigned* part   = (unsigned*)((char*)d_ws + 256 + NPTS * 4);

    int nparts = 8;
    while (nparts > 1 &&
           256 + (size_t)NPTS * 4 + (size_t)nparts * NPTS * KNN * 4 > ws_size) {
        nparts >>= 1;
    }
    const int plen = NPTS / nparts;
    const int samp = 2048 / nparts;   // total sample = 2048 candidates

    hipMemsetAsync(d_ws, 0, 64, stream);

    knn_sample_kernel<<<dim3(NPTS / 256, nparts), 256, 0, stream>>>(pc, part, plen, samp);
    tau_kernel<<<NPTS / 256, 256, 0, stream>>>(part, wts, nparts, accum, tauArr);
    knn_main_kernel<<<dim3(NPTS / 256, nparts), 256, 0, stream>>>(pc, tauArr, part, plen);
    loss_kernel<<<dim3(NPTS / 256, SEQV), 256, 0, stream>>>(flow, wts, part, nparts, accum);
    finalize_kernel<<<1, 1, 0, stream>>>(accum, out);
}

// Round 3
// 337.379 us; speedup vs baseline: 1.2715x; 1.1107x over previous
//
#include <hip/hip_runtime.h>
#include <math.h>

#define NPTS 16384
#define KNN  16
#define SEQV 8
#define CAP  25      // odd stride -> conflict-free LDS appends; 25*4*256 = 25.6 KB/block

__device__ __forceinline__ unsigned umin_(unsigned a, unsigned b) { return a < b ? a : b; }
__device__ __forceinline__ unsigned umax_(unsigned a, unsigned b) { return a > b ? a : b; }

// merge one key into sorted ascending keys[16]
__device__ __forceinline__ void merge_one(unsigned keys[KNN], unsigned kk) {
    if (kk < keys[KNN - 1]) {
#pragma unroll
        for (int u = 0; u < KNN; ++u) {
            unsigned lo = umin_(kk, keys[u]);
            kk = umax_(kk, keys[u]);
            keys[u] = lo;
        }
    }
}

// ---------------------------------------------------------------------------
// A: cold sample scan. Grid (64, nparts). Partition p scans its first `samp`
// candidates, writes top-16 packed keys. key = (d2 bits & 0xFFFFC000) | j.
// ---------------------------------------------------------------------------
__global__ __launch_bounds__(256) void knn_sample_kernel(
    const float* __restrict__ pc, unsigned* __restrict__ part, int plen, int samp)
{
    const int i = blockIdx.x * 256 + threadIdx.x;
    const int p = blockIdx.y;

    const float qx = pc[3 * i + 0];
    const float qy = pc[3 * i + 1];
    const float qz = pc[3 * i + 2];

    unsigned keys[KNN];
#pragma unroll
    for (int t = 0; t < KNN; ++t) keys[t] = 0xFFFFFFFFu;

    const int jbeg = p * plen;
    const int jend = jbeg + samp;

#pragma unroll 1
    for (int j = jbeg; j < jend; j += 4) {
        const int ju = __builtin_amdgcn_readfirstlane(j);
        const float* cb = pc + 3 * (size_t)ju;
        unsigned kb[4];
#pragma unroll
        for (int q = 0; q < 4; ++q) {
            float dx = qx - cb[3 * q + 0];
            float dy = qy - cb[3 * q + 1];
            float dz = qz - cb[3 * q + 2];
            float d2 = fmaf(dx, dx, fmaf(dy, dy, dz * dz));
            kb[q] = (__float_as_uint(d2) & 0xFFFFC000u) | (unsigned)(j + q);
        }
#pragma unroll
        for (int q = 0; q < 4; ++q) merge_one(keys, kb[q]);
    }

    unsigned* dst = part + ((size_t)p * NPTS + i) * KNN;
#pragma unroll
    for (int t = 0; t < KNN; ++t) dst[t] = keys[t];
}

// ---------------------------------------------------------------------------
// A2: tau[i] = 16th-smallest key of the merged sample. Also weight sum.
// ---------------------------------------------------------------------------
__global__ __launch_bounds__(256) void tau_kernel(
    const unsigned* __restrict__ part, const float* __restrict__ w, int nparts,
    float* __restrict__ accum, unsigned* __restrict__ tauArr)
{
    const int i = blockIdx.x * 256 + threadIdx.x;

    unsigned keys[KNN];
#pragma unroll
    for (int t = 0; t < KNN; ++t) keys[t] = 0xFFFFFFFFu;

#pragma unroll 1
    for (int p = 0; p < nparts; ++p) {
        const unsigned* src = part + ((size_t)p * NPTS + i) * KNN;
#pragma unroll
        for (int t = 0; t < KNN; ++t) merge_one(keys, src[t]);
    }
    tauArr[i] = keys[KNN - 1];

    float wi = w[i];
#pragma unroll
    for (int off = 32; off > 0; off >>= 1) wi += __shfl_down(wi, off);
    if ((threadIdx.x & 63) == 0) atomicAdd(&accum[1], wi);
}

// ---------------------------------------------------------------------------
// B: main scan, threshold filter + deferred LDS-buffered selection.
// Grid (64, nparts). Candidate coords via wave-uniform scalar base pointer.
// ---------------------------------------------------------------------------
__global__ __launch_bounds__(256) void knn_main_kernel(
    const float* __restrict__ pc, const unsigned* __restrict__ tauArr,
    unsigned* __restrict__ part, int plen)
{
    __shared__ unsigned sbuf[256 * CAP];
    unsigned* buf = &sbuf[threadIdx.x * CAP];

    const int i = blockIdx.x * 256 + threadIdx.x;
    const int p = blockIdx.y;

    const float qx = pc[3 * i + 0];
    const float qy = pc[3 * i + 1];
    const float qz = pc[3 * i + 2];

    unsigned tau = tauArr[i];
    unsigned keys[KNN];
#pragma unroll
    for (int t = 0; t < KNN; ++t) keys[t] = 0xFFFFFFFFu;
    int cnt = 0;

    const int jbeg = p * plen;
    const int jend = jbeg + plen;

#pragma unroll 1
    for (int j = jbeg; j < jend; j += 8) {
        const int ju = __builtin_amdgcn_readfirstlane(j);
        const float* cb = pc + 3 * (size_t)ju;   // uniform -> s_load bursts
#pragma unroll
        for (int q = 0; q < 8; ++q) {
            float dx = qx - cb[3 * q + 0];
            float dy = qy - cb[3 * q + 1];
            float dz = qz - cb[3 * q + 2];
            float d2 = fmaf(dx, dx, fmaf(dy, dy, dz * dz));
            unsigned key = (__float_as_uint(d2) & 0xFFFFC000u) | (unsigned)(j + q);
            if (key <= tau) {            // tau >= global 16th key -> exact
                buf[cnt] = key;
                cnt++;
            }
        }
        // headroom: entering a batch cnt <= CAP-9; appends <= 8 -> max CAP-1
        if (cnt >= CAP - 8) {
#pragma unroll 1
            for (int t = 0; t < cnt; ++t) merge_one(keys, buf[t]);
            cnt = 0;
            tau = umin_(tau, keys[KNN - 1]);   // tightened, still >= global 16th
        }
    }

#pragma unroll 1
    for (int t = 0; t < cnt; ++t) merge_one(keys, buf[t]);

    unsigned* dst = part + ((size_t)p * NPTS + i) * KNN;
#pragma unroll
    for (int t = 0; t < KNN; ++t) dst[t] = keys[t];
}

// ---------------------------------------------------------------------------
// C: final merge across partitions + radius filter -> ids[N][16]
// ---------------------------------------------------------------------------
__global__ __launch_bounds__(256) void final_merge_kernel(
    const unsigned* __restrict__ part, int nparts, int* __restrict__ ids)
{
    const int i = blockIdx.x * 256 + threadIdx.x;

    unsigned keys[KNN];
#pragma unroll
    for (int t = 0; t < KNN; ++t) keys[t] = 0xFFFFFFFFu;

#pragma unroll 1
    for (int p = 0; p < nparts; ++p) {
        const unsigned* src = part + ((size_t)p * NPTS + i) * KNN;
#pragma unroll
        for (int t = 0; t < KNN; ++t) merge_one(keys, src[t]);
    }

    const int id0 = (int)(keys[0] & 0x3FFFu);
    int* dst = ids + (size_t)i * KNN;
#pragma unroll
    for (int t = 0; t < KNN; ++t) {
        float d2t = __uint_as_float(keys[t] & 0xFFFFC000u);
        int   j   = (int)(keys[t] & 0x3FFFu);
        dst[t] = (d2t > 1.0f) ? id0 : j;
    }
}

// ---------------------------------------------------------------------------
// D: gather-only loss. Grid (128, SEQV). thread = (query, k-half of 8).
// accum[0] += sum w_i * norm
// ---------------------------------------------------------------------------
__global__ __launch_bounds__(256) void loss_kernel(
    const float* __restrict__ flow, const float* __restrict__ w,
    const int* __restrict__ ids, float* __restrict__ accum)
{
    const int qloc = threadIdx.x & 127;
    const int half = threadIdx.x >> 7;
    const int i = blockIdx.x * 128 + qloc;
    const int s = blockIdx.y;

    const float* fs = flow + (size_t)s * NPTS * 3;
    const float fx = fs[3 * i + 0];
    const float fy = fs[3 * i + 1];
    const float fz = fs[3 * i + 2];

    const int* idp = ids + (size_t)i * KNN + half * 8;

    float sum = 0.0f;
#pragma unroll
    for (int q = 0; q < 8; ++q) {
        int j = idp[q];
        float dx = fx - fs[3 * j + 0];
        float dy = fy - fs[3 * j + 1];
        float dz = fz - fs[3 * j + 2];
        float sq = fmaf(dx, dx, fmaf(dy, dy, dz * dz));
        sum += (sq > 0.0f) ? sqrtf(sq) : 0.0f;
    }

    float contrib = w[i] * sum;
#pragma unroll
    for (int off = 32; off > 0; off >>= 1) contrib += __shfl_down(contrib, off);

    __shared__ float sc[4];
    const int lane = threadIdx.x & 63;
    const int wv   = threadIdx.x >> 6;
    if (lane == 0) sc[wv] = contrib;
    __syncthreads();
    if (threadIdx.x == 0)
        atomicAdd(&accum[0], sc[0] + sc[1] + sc[2] + sc[3]);
}

__global__ void finalize_kernel(const float* __restrict__ accum, float* __restrict__ out)
{
    float a  = accum[0];
    float ws = accum[1];
    float v  = a / (float)(KNN * SEQV);
    out[0] = (ws > 0.0f) ? (v / ws) : v;
}

extern "C" void kernel_launch(void* const* d_in, const int* in_sizes, int n_in,
                              void* d_out, int out_size, void* d_ws, size_t ws_size,
                              hipStream_t stream)
{
    const float* pc   = (const float*)d_in[0];   // (1, N, 3)
    const float* flow = (const float*)d_in[1];   // (SEQ, N, 3)
    const float* wts  = (const float*)d_in[2];   // (N,)
    float* out = (float*)d_out;

    float*    accum  = (float*)d_ws;
    unsigned* tauArr = (unsigned*)((char*)d_ws + 256);
    int*      ids    = (int*)((char*)d_ws + 256 + NPTS * 4);
    unsigned* part   = (unsigned*)((char*)d_ws + 256 + NPTS * 4 + (size_t)NPTS * KNN * 4);

    const size_t fixed = 256 + NPTS * 4 + (size_t)NPTS * KNN * 4;
    int nparts = 16;
    while (nparts > 1 &&
           fixed + (size_t)nparts * NPTS * KNN * 4 > ws_size) {
        nparts >>= 1;
    }
    const int plen = NPTS / nparts;
    const int samp = 2048 / nparts;   // total sample = 2048 candidates

    hipMemsetAsync(d_ws, 0, 64, stream);

    knn_sample_kernel<<<dim3(NPTS / 256, nparts), 256, 0, stream>>>(pc, part, plen, samp);
    tau_kernel<<<NPTS / 256, 256, 0, stream>>>(part, wts, nparts, accum, tauArr);
    knn_main_kernel<<<dim3(NPTS / 256, nparts), 256, 0, stream>>>(pc, tauArr, part, plen);
    final_merge_kernel<<<NPTS / 256, 256, 0, stream>>>(part, nparts, ids);
    loss_kernel<<<dim3(NPTS / 128, SEQV), 256, 0, stream>>>(flow, wts, ids, accum);
    finalize_kernel<<<1, 1, 0, stream>>>(accum, out);
}